// Round 8
// baseline (199.187 us; speedup 1.0000x reference)
//
#include <hip/hip_runtime.h>
#include <hip/hip_fp16.h>
#include <math.h>

// A3TGCN reduced form (H0 == 0 => r-branch dead, GRU collapses):
//   agg[n,p] = dinv[n] * ( sum_{e: dst=n} xs[src[e],p] + xs[n,p] ),  xs = dinv .* x
//   z = sigmoid(agg*az[c]+cz[c]); h = tanh(agg*ah[c]+ch[c])
//   out[n,:] = (sum_p probs[p]*(1-z)*h) @ out_w + out_b
//
// Round 8: k_aggF was TLP-starved (782 blocks, per-lane chain of ~8 dependent
// gathers, occ 33%, VALUBusy 27% — 10x above the ~6 us L2/address floors).
// Mean degree 32 means unrolling can't create ILP (runs too short), so trade
// ILP for TLP: 8 lanes/node, 3125 blocks, ~4 gathers per lane chain.
// binA/binB untouched (isolate the variable; they surface in top-5 next).

#define PERIODS 12
#define BSZ     256              // nodes per bucket (2^BSH)
#define BSH     8
#define STRIDE  9216             // bucket capacity: mean 8192 + 11 sigma
#define SRCBITS 17               // N = 100000 < 2^17
#define SMASK   ((1 << SRCBITS) - 1)
#define CH      4096             // edges per k_binA block

struct Consts {
    float az[4], cz[4], ah[4], ch[4], probs[PERIODS];
};

// ---------------- fp8 e4m3 helpers (builtin fast path + manual fallback) ----
typedef float vf2 __attribute__((ext_vector_type(2)));

__device__ __forceinline__ float dec1_manual(unsigned b) {
    unsigned e = (b >> 3) & 15u, m = b & 7u;
    float v = e ? __uint_as_float(((e + 120u) << 23) | (m << 20))
                : (float)m * 0.001953125f;          // 2^-9 subnormal step
    return (b & 0x80u) ? -v : v;
}

__device__ __forceinline__ void dec4(unsigned u, float* o) {
#if __has_builtin(__builtin_amdgcn_cvt_pk_f32_fp8)
    vf2 lo = __builtin_amdgcn_cvt_pk_f32_fp8((int)u, false);
    vf2 hi = __builtin_amdgcn_cvt_pk_f32_fp8((int)u, true);
    o[0] = lo.x; o[1] = lo.y; o[2] = hi.x; o[3] = hi.y;
#else
    o[0] = dec1_manual(u & 255u);
    o[1] = dec1_manual((u >> 8) & 255u);
    o[2] = dec1_manual((u >> 16) & 255u);
    o[3] = dec1_manual(u >> 24);
#endif
}

__device__ __forceinline__ unsigned enc1_manual(float x) {
    unsigned s = (__float_as_uint(x) >> 24) & 0x80u;
    float a = fabsf(x);
    if (!(a > 0.f)) return s;
    a = fminf(a, 448.f);
    int eb = (int)(__float_as_uint(a) >> 23) - 127;
    int e = eb < -6 ? -6 : eb;
    float q = rintf(a * exp2f((float)(3 - e)));
    if (q >= 16.f) { e++; q = rintf(a * exp2f((float)(3 - e))); }
    if (e > 8) return s | 0x7Eu;                    // clamp to 448
    int m = (int)q;
    unsigned ee, mm;
    if (m >= 8) { ee = (unsigned)(e + 7); mm = (unsigned)(m - 8); }
    else        { ee = 0u; mm = (unsigned)m; }      // subnormal (e == -6)
    return s | (ee << 3) | mm;
}

__device__ __forceinline__ unsigned pk4(float a, float b, float c, float d) {
#if __has_builtin(__builtin_amdgcn_cvt_pk_fp8_f32)
    int v = __builtin_amdgcn_cvt_pk_fp8_f32(a, b, 0, false);
    v = __builtin_amdgcn_cvt_pk_fp8_f32(c, d, v, true);
    return (unsigned)v;
#else
    return enc1_manual(a) | (enc1_manual(b) << 8) |
           (enc1_manual(c) << 16) | (enc1_manual(d) << 24);
#endif
}

// ---------------------------------------------------------------------------

// Thread 0 computes folded constants; all threads zero gcur.
__global__ __launch_bounds__(512) void k_setup(const float* conv_z_w, const float* conv_z_b,
                        const float* lin_z_w, const float* lin_z_b,
                        const float* conv_h_w, const float* conv_h_b,
                        const float* lin_h_w, const float* lin_h_b,
                        const float* att, Consts* C, int* gcur, int NB)
{
    int t = threadIdx.x;
    for (int i = t; i < NB; i += 512) gcur[i] = 0;
    if (t == 0) {
        for (int c = 0; c < 4; ++c) {
            float az = 0.f, cz = 0.f, ah = 0.f, ch = 0.f;
            for (int k = 0; k < 4; ++k) {
                az += conv_z_w[k] * lin_z_w[k * 4 + c];
                cz += conv_z_b[k] * lin_z_w[k * 4 + c];
                ah += conv_h_w[k] * lin_h_w[k * 4 + c];
                ch += conv_h_b[k] * lin_h_w[k * 4 + c];
            }
            C->az[c] = az; C->cz[c] = cz + lin_z_b[c];
            C->ah[c] = ah; C->ch[c] = ch + lin_h_b[c];
        }
        float m = att[0];
        for (int p = 1; p < PERIODS; ++p) m = fmaxf(m, att[p]);
        float e[PERIODS]; float s = 0.f;
        for (int p = 0; p < PERIODS; ++p) { e[p] = expf(att[p] - m); s += e[p]; }
        for (int p = 0; p < PERIODS; ++p) C->probs[p] = e[p] / s;
    }
}

// Pass 1: bin edges by dst bucket. CH=4096 -> 38 KB LDS -> 4 blocks/CU.
__global__ __launch_bounds__(512) void k_binA(const int* __restrict__ ei,
                                              int* __restrict__ gcur,
                                              int* __restrict__ binned, int E) {
    __shared__ int hist[512];
    __shared__ int scn[512];
    __shared__ int gdel[512];
    __shared__ int sv[CH];
    __shared__ int sa[CH];
    int t = threadIdx.x;
    hist[t] = 0;
    __syncthreads();
    int base = blockIdx.x * CH;
    int lim = min(E - base, CH);
    #pragma unroll
    for (int k = 0; k < CH / 512; ++k) {
        int i = t + k * 512;
        if (i < lim) atomicAdd(&hist[ei[E + base + i] >> BSH], 1);
    }
    __syncthreads();
    int v = hist[t];
    scn[t] = v;
    __syncthreads();
    for (int off = 1; off < 512; off <<= 1) {
        int tmp = (t >= off) ? scn[t - off] : 0;
        __syncthreads();
        scn[t] += tmp;
        __syncthreads();
    }
    int excl = scn[t] - v;
    int g = (v > 0) ? atomicAdd(&gcur[t], v) : 0;
    gdel[t] = t * STRIDE + g - excl;
    hist[t] = excl;
    __syncthreads();
    #pragma unroll
    for (int k = 0; k < CH / 512; ++k) {
        int i = t + k * 512;
        if (i < lim) {
            int s = ei[base + i];
            int d = ei[E + base + i];
            int b = d >> BSH;
            int pos = atomicAdd(&hist[b], 1);
            sv[pos] = ((d & (BSZ - 1)) << SRCBITS) | s;
            sa[pos] = gdel[b] + pos;
        }
    }
    __syncthreads();
    for (int j = t; j < lim; j += 512)
        binned[sa[j]] = sv[j];
}

// Pass 2: counting-sort each bucket's edges by dst node; emit src-only list
// + per-node start offsets. LDS-staged, coalesced flush, no global atomics.
__global__ __launch_bounds__(512) void k_binB(const int* __restrict__ binned,
                                              const int* __restrict__ gcur,
                                              int* __restrict__ nodesorted,
                                              int* __restrict__ nofs) {
    __shared__ int hist[BSZ];
    __shared__ int scn[512];
    __shared__ int cur[BSZ];
    __shared__ int sorted[STRIDE];
    int b = blockIdx.x, t = threadIdx.x;
    if (t < BSZ) hist[t] = 0;
    __syncthreads();
    int cnt = gcur[b];
    const int* bb = binned + b * STRIDE;
    for (int i = t; i < cnt; i += 512)
        atomicAdd(&hist[bb[i] >> SRCBITS], 1);
    __syncthreads();
    int v = (t < BSZ) ? hist[t] : 0;
    scn[t] = v;
    __syncthreads();
    for (int off = 1; off < 512; off <<= 1) {
        int tmp = (t >= off) ? scn[t - off] : 0;
        __syncthreads();
        scn[t] += tmp;
        __syncthreads();
    }
    if (t < BSZ) {
        int excl = scn[t] - v;
        cur[t] = excl;
        nofs[b * BSZ + t] = excl;
    }
    __syncthreads();
    for (int i = t; i < cnt; i += 512) {
        int pv = bb[i];
        int pos = atomicAdd(&cur[pv >> SRCBITS], 1);
        sorted[pos] = pv & SMASK;
    }
    __syncthreads();
    int* dst = nodesorted + b * STRIDE;
    for (int j = t; j < cnt; j += 512)
        dst[j] = sorted[j];
}

// Per node: degree from nofs diffs -> dinv + fp8 xs row (16 B).
__global__ void k_prep(const int* __restrict__ nofs, const int* __restrict__ gcur,
                       const float* __restrict__ x, float* __restrict__ dinv,
                       uint4* __restrict__ xs8, int N) {
    int n = blockIdx.x * blockDim.x + threadIdx.x;
    if (n >= N) return;
    int b = n >> BSH, ln = n & (BSZ - 1);
    int start = nofs[b * BSZ + ln];
    int end = (ln == BSZ - 1) ? gcur[b] : nofs[b * BSZ + ln + 1];
    float di = rsqrtf((float)(end - start) + 1.0f);   // +1 = self loop
    dinv[n] = di;
    const float4* xv = (const float4*)(x + (size_t)n * PERIODS);
    float4 v0 = xv[0], v1 = xv[1], v2 = xv[2];
    uint4 r;
    r.x = pk4(v0.x * di, v0.y * di, v0.z * di, v0.w * di);
    r.y = pk4(v1.x * di, v1.y * di, v1.z * di, v1.w * di);
    r.z = pk4(v2.x * di, v2.y * di, v2.z * di, v2.w * di);
    r.w = 0;
    xs8[n] = r;
}

__device__ __forceinline__ void accdec(float* acc, uint4 r) {
    float f[PERIODS];
    dec4(r.x, f + 0); dec4(r.y, f + 4); dec4(r.z, f + 8);
    #pragma unroll
    for (int k = 0; k < PERIODS; ++k) acc[k] += f[k];
}

// 8 threads per node; each lane's chain is only ~4 dependent gathers; TLP
// (3125 blocks) hides the latency. shfl combine; lane 0 runs epilogue.
__global__ __launch_bounds__(256) void k_aggF(const int* __restrict__ nodesorted,
                                              const int* __restrict__ nofs,
                                              const int* __restrict__ gcur,
                                              const float* __restrict__ dinv,
                                              const uint4* __restrict__ xs8,
                                              const Consts* __restrict__ C,
                                              const float* __restrict__ out_w,
                                              const float* __restrict__ out_b,
                                              float* __restrict__ out, int N) {
    int tid = blockIdx.x * 256 + threadIdx.x;
    int n = tid >> 3;
    int lane = tid & 7;
    if (n >= N) return;
    int b = n >> BSH, ln = n & (BSZ - 1);

    int start = nofs[b * BSZ + ln];
    int end = (ln == BSZ - 1) ? gcur[b] : nofs[b * BSZ + ln + 1];
    const int* ns = nodesorted + b * STRIDE;

    float acc[PERIODS];
    #pragma unroll
    for (int k = 0; k < PERIODS; ++k) acc[k] = 0.f;

    for (int i = start + lane; i < end; i += 8) {
        uint4 r0 = xs8[ns[i]];
        accdec(acc, r0);
    }

    // combine the 8 lanes of this node
    #pragma unroll
    for (int k = 0; k < PERIODS; ++k) {
        acc[k] += __shfl_xor(acc[k], 1);
        acc[k] += __shfl_xor(acc[k], 2);
        acc[k] += __shfl_xor(acc[k], 4);
    }

    if (lane != 0) return;

    {   // self term (di-scaled fp8 row)
        float f[PERIODS];
        uint4 r = xs8[n];
        dec4(r.x, f + 0); dec4(r.y, f + 4); dec4(r.z, f + 8);
        #pragma unroll
        for (int k = 0; k < PERIODS; ++k) acc[k] += f[k];
    }

    float di = dinv[n];
    float hacc[4] = {0.f, 0.f, 0.f, 0.f};
    #pragma unroll
    for (int p = 0; p < PERIODS; ++p) {
        float ap = di * acc[p];
        float pr = C->probs[p];
        #pragma unroll
        for (int c = 0; c < 4; ++c) {
            float zz = 1.f / (1.f + __expf(-(ap * C->az[c] + C->cz[c])));
            float hh = tanhf(ap * C->ah[c] + C->ch[c]);
            hacc[c] += pr * (1.f - zz) * hh;
        }
    }
    float o[PERIODS];
    #pragma unroll
    for (int f = 0; f < PERIODS; ++f) {
        float v = out_b[f];
        #pragma unroll
        for (int c = 0; c < 4; ++c) v += hacc[c] * out_w[c * PERIODS + f];
        o[f] = v;
    }
    float4* ov = (float4*)(out + (size_t)n * PERIODS);
    ov[0] = make_float4(o[0], o[1], o[2],  o[3]);
    ov[1] = make_float4(o[4], o[5], o[6],  o[7]);
    ov[2] = make_float4(o[8], o[9], o[10], o[11]);
}

extern "C" void kernel_launch(void* const* d_in, const int* in_sizes, int n_in,
                              void* d_out, int out_size, void* d_ws, size_t ws_size,
                              hipStream_t stream) {
    const float* x        = (const float*)d_in[0];
    const int*   ei       = (const int*)d_in[1];
    const float* conv_z_w = (const float*)d_in[2];
    const float* conv_z_b = (const float*)d_in[3];
    const float* lin_z_w  = (const float*)d_in[4];
    const float* lin_z_b  = (const float*)d_in[5];
    const float* conv_h_w = (const float*)d_in[10];
    const float* conv_h_b = (const float*)d_in[11];
    const float* lin_h_w  = (const float*)d_in[12];
    const float* lin_h_b  = (const float*)d_in[13];
    const float* att      = (const float*)d_in[14];
    const float* out_w    = (const float*)d_in[15];
    const float* out_b    = (const float*)d_in[16];
    float* out = (float*)d_out;

    const int N  = in_sizes[0] / PERIODS;
    const int E  = in_sizes[1] / 2;
    const int NB = (N + BSZ - 1) / BSZ;          // 391 buckets
    const int gA = (E + CH - 1) / CH;            // binning blocks

    // workspace layout (256B-aligned regions); total ~31 MB
    char* ws = (char*)d_ws;
    size_t off = 0;
    Consts* consts     = (Consts*)(ws + off);  off += (sizeof(Consts) + 255) & ~255ull;
    int*    gcur       = (int*)(ws + off);     off += ((size_t)NB * 4 + 255) & ~255ull;
    float*  dinv       = (float*)(ws + off);   off += ((size_t)N * 4 + 255) & ~255ull;
    uint4*  xs8        = (uint4*)(ws + off);   off += ((size_t)(N + 256) * 16 + 255) & ~255ull;
    int*    binned     = (int*)(ws + off);     off += ((size_t)NB * STRIDE * 4 + 255) & ~255ull;
    int*    nodesorted = (int*)(ws + off);     off += ((size_t)NB * STRIDE * 4 + 255) & ~255ull;
    int*    nofs       = (int*)(ws + off);     off += ((size_t)NB * BSZ * 4 + 255) & ~255ull;
    (void)ws_size; (void)n_in; (void)out_size;

    k_setup<<<1, 512, 0, stream>>>(conv_z_w, conv_z_b, lin_z_w, lin_z_b,
                                   conv_h_w, conv_h_b, lin_h_w, lin_h_b, att,
                                   consts, gcur, NB);
    k_binA<<<gA, 512, 0, stream>>>(ei, gcur, binned, E);
    k_binB<<<NB, 512, 0, stream>>>(binned, gcur, nodesorted, nofs);
    k_prep<<<(N + 255) / 256, 256, 0, stream>>>(nofs, gcur, x, dinv, xs8, N);
    k_aggF<<<(8 * N + 255) / 256, 256, 0, stream>>>(nodesorted, nofs, gcur, dinv,
                                                    xs8, consts, out_w, out_b, out, N);
}

// Round 9
// 185.862 us; speedup vs baseline: 1.0717x; 1.0717x over previous
//
#include <hip/hip_runtime.h>
#include <hip/hip_fp16.h>
#include <math.h>

// A3TGCN reduced form (H0 == 0 => r-branch dead, GRU collapses):
//   agg[n,p] = dinv[n] * ( sum_{e: dst=n} xs[src[e],p] + xs[n,p] ),  xs = dinv .* x
//   z = sigmoid(agg*az[c]+cz[c]); h = tanh(agg*ah[c]+ch[c])
//   out[n,:] = (sum_p probs[p]*(1-z)*h) @ out_w + out_b
//
// Round 9: gather is per-CU MSHR-bound (~57 us floor, invariant to occupancy
// r6-r8). So: shorten the pipeline around it. binB's global sorted round-trip
// is gone — k_prep emits per-node degree (deg16) + fp8 xs8; fused k_agg
// (per HALF-bucket, 782 blocks) scans deg16 -> local offsets, cursor-scatters
// its half's edges into LDS (1 atomic/edge), register-gathers 4 lanes/node,
// and runs the epilogue inline. Sort work hides under other blocks' gather
// latency. 4 dispatches total (was 6).

#define PERIODS 12
#define BSZ     256              // nodes per bucket (2^BSH)
#define BSH     8
#define HALF    128              // nodes per k_agg block
#define STRIDE  9216             // bucket capacity: mean 8192 + 11 sigma
#define SCAP    4800             // half-bucket edge capacity: 4096 + 11 sigma
#define SRCBITS 17               // N = 100000 < 2^17
#define SMASK   ((1 << SRCBITS) - 1)
#define CH      4096             // edges per k_binA block

struct Consts {
    float az[4], cz[4], ah[4], ch[4], probs[PERIODS];
};

// ---------------- fp8 e4m3 helpers (builtin fast path + manual fallback) ----
typedef float vf2 __attribute__((ext_vector_type(2)));

__device__ __forceinline__ float dec1_manual(unsigned b) {
    unsigned e = (b >> 3) & 15u, m = b & 7u;
    float v = e ? __uint_as_float(((e + 120u) << 23) | (m << 20))
                : (float)m * 0.001953125f;          // 2^-9 subnormal step
    return (b & 0x80u) ? -v : v;
}

__device__ __forceinline__ void dec4(unsigned u, float* o) {
#if __has_builtin(__builtin_amdgcn_cvt_pk_f32_fp8)
    vf2 lo = __builtin_amdgcn_cvt_pk_f32_fp8((int)u, false);
    vf2 hi = __builtin_amdgcn_cvt_pk_f32_fp8((int)u, true);
    o[0] = lo.x; o[1] = lo.y; o[2] = hi.x; o[3] = hi.y;
#else
    o[0] = dec1_manual(u & 255u);
    o[1] = dec1_manual((u >> 8) & 255u);
    o[2] = dec1_manual((u >> 16) & 255u);
    o[3] = dec1_manual(u >> 24);
#endif
}

__device__ __forceinline__ unsigned enc1_manual(float x) {
    unsigned s = (__float_as_uint(x) >> 24) & 0x80u;
    float a = fabsf(x);
    if (!(a > 0.f)) return s;
    a = fminf(a, 448.f);
    int eb = (int)(__float_as_uint(a) >> 23) - 127;
    int e = eb < -6 ? -6 : eb;
    float q = rintf(a * exp2f((float)(3 - e)));
    if (q >= 16.f) { e++; q = rintf(a * exp2f((float)(3 - e))); }
    if (e > 8) return s | 0x7Eu;                    // clamp to 448
    int m = (int)q;
    unsigned ee, mm;
    if (m >= 8) { ee = (unsigned)(e + 7); mm = (unsigned)(m - 8); }
    else        { ee = 0u; mm = (unsigned)m; }      // subnormal (e == -6)
    return s | (ee << 3) | mm;
}

__device__ __forceinline__ unsigned pk4(float a, float b, float c, float d) {
#if __has_builtin(__builtin_amdgcn_cvt_pk_fp8_f32)
    int v = __builtin_amdgcn_cvt_pk_fp8_f32(a, b, 0, false);
    v = __builtin_amdgcn_cvt_pk_fp8_f32(c, d, v, true);
    return (unsigned)v;
#else
    return enc1_manual(a) | (enc1_manual(b) << 8) |
           (enc1_manual(c) << 16) | (enc1_manual(d) << 24);
#endif
}

// ---------------------------------------------------------------------------

// Thread 0 computes folded constants; all threads zero gcur + deg16 tail.
__global__ __launch_bounds__(512) void k_setup(const float* conv_z_w, const float* conv_z_b,
                        const float* lin_z_w, const float* lin_z_b,
                        const float* conv_h_w, const float* conv_h_b,
                        const float* lin_h_w, const float* lin_h_b,
                        const float* att, Consts* C, int* gcur, int NB,
                        unsigned short* deg16, int N, int NPAD)
{
    int t = threadIdx.x;
    for (int i = t; i < NB; i += 512) gcur[i] = 0;
    for (int i = N + t; i < NPAD; i += 512) deg16[i] = 0;
    if (t == 0) {
        for (int c = 0; c < 4; ++c) {
            float az = 0.f, cz = 0.f, ah = 0.f, ch = 0.f;
            for (int k = 0; k < 4; ++k) {
                az += conv_z_w[k] * lin_z_w[k * 4 + c];
                cz += conv_z_b[k] * lin_z_w[k * 4 + c];
                ah += conv_h_w[k] * lin_h_w[k * 4 + c];
                ch += conv_h_b[k] * lin_h_w[k * 4 + c];
            }
            C->az[c] = az; C->cz[c] = cz + lin_z_b[c];
            C->ah[c] = ah; C->ch[c] = ch + lin_h_b[c];
        }
        float m = att[0];
        for (int p = 1; p < PERIODS; ++p) m = fmaxf(m, att[p]);
        float e[PERIODS]; float s = 0.f;
        for (int p = 0; p < PERIODS; ++p) { e[p] = expf(att[p] - m); s += e[p]; }
        for (int p = 0; p < PERIODS; ++p) C->probs[p] = e[p] / s;
    }
}

// Pass 1: bin edges by dst bucket (unchanged from round 7).
__global__ __launch_bounds__(512) void k_binA(const int* __restrict__ ei,
                                              int* __restrict__ gcur,
                                              int* __restrict__ binned, int E) {
    __shared__ int hist[512];
    __shared__ int scn[512];
    __shared__ int gdel[512];
    __shared__ int sv[CH];
    __shared__ int sa[CH];
    int t = threadIdx.x;
    hist[t] = 0;
    __syncthreads();
    int base = blockIdx.x * CH;
    int lim = min(E - base, CH);
    #pragma unroll
    for (int k = 0; k < CH / 512; ++k) {
        int i = t + k * 512;
        if (i < lim) atomicAdd(&hist[ei[E + base + i] >> BSH], 1);
    }
    __syncthreads();
    int v = hist[t];
    scn[t] = v;
    __syncthreads();
    for (int off = 1; off < 512; off <<= 1) {
        int tmp = (t >= off) ? scn[t - off] : 0;
        __syncthreads();
        scn[t] += tmp;
        __syncthreads();
    }
    int excl = scn[t] - v;
    int g = (v > 0) ? atomicAdd(&gcur[t], v) : 0;
    gdel[t] = t * STRIDE + g - excl;
    hist[t] = excl;
    __syncthreads();
    #pragma unroll
    for (int k = 0; k < CH / 512; ++k) {
        int i = t + k * 512;
        if (i < lim) {
            int s = ei[base + i];
            int d = ei[E + base + i];
            int b = d >> BSH;
            int pos = atomicAdd(&hist[b], 1);
            sv[pos] = ((d & (BSZ - 1)) << SRCBITS) | s;
            sa[pos] = gdel[b] + pos;
        }
    }
    __syncthreads();
    for (int j = t; j < lim; j += 512)
        binned[sa[j]] = sv[j];
}

// Per bucket: LDS degree histogram -> deg16 + fp8 xs rows (16 B each).
__global__ __launch_bounds__(512) void k_prep(const int* __restrict__ binned,
                                              const int* __restrict__ gcur,
                                              const float* __restrict__ x,
                                              unsigned short* __restrict__ deg16,
                                              uint4* __restrict__ xs8, int N) {
    __shared__ int ldeg[BSZ];
    int b = blockIdx.x, t = threadIdx.x;
    if (t < BSZ) ldeg[t] = 0;
    __syncthreads();
    int cnt = gcur[b];
    const int* bb = binned + b * STRIDE;
    for (int i = t; i < cnt; i += 512)
        atomicAdd(&ldeg[bb[i] >> SRCBITS], 1);
    __syncthreads();
    if (t < BSZ) {
        int n = (b << BSH) + t;
        if (n < N) {
            int dg = ldeg[t];
            deg16[n] = (unsigned short)dg;
            float di = rsqrtf((float)dg + 1.0f);      // +1 = self loop
            const float4* xv = (const float4*)(x + (size_t)n * PERIODS);
            float4 v0 = xv[0], v1 = xv[1], v2 = xv[2];
            uint4 r;
            r.x = pk4(v0.x * di, v0.y * di, v0.z * di, v0.w * di);
            r.y = pk4(v1.x * di, v1.y * di, v1.z * di, v1.w * di);
            r.z = pk4(v2.x * di, v2.y * di, v2.z * di, v2.w * di);
            r.w = 0;
            xs8[n] = r;
        }
    }
}

__device__ __forceinline__ void accdec(float* acc, uint4 r) {
    float f[PERIODS];
    dec4(r.x, f + 0); dec4(r.y, f + 4); dec4(r.z, f + 8);
    #pragma unroll
    for (int k = 0; k < PERIODS; ++k) acc[k] += f[k];
}

// Fused per HALF-bucket: scan deg16 -> local offsets; cursor-scatter own
// half's edges into LDS-sorted (1 atomic/edge); 4 lanes/node register
// gather; shfl combine; inline epilogue. No global sorted array, no partials.
__global__ __launch_bounds__(512) void k_agg(const int* __restrict__ binned,
                                             const int* __restrict__ gcur,
                                             const unsigned short* __restrict__ deg16,
                                             const uint4* __restrict__ xs8,
                                             const Consts* __restrict__ C,
                                             const float* __restrict__ out_w,
                                             const float* __restrict__ out_b,
                                             float* __restrict__ out, int N) {
    __shared__ int ofs[HALF + 1];
    __shared__ int cur[HALF];
    __shared__ int scn[HALF];
    __shared__ int sorted[SCAP];
    int t = threadIdx.x;
    int b = blockIdx.x >> 1;
    int halfSel = blockIdx.x & 1;
    int nbase = (b << BSH) + halfSel * HALF;

    // offsets from deg16 (128-wide Hillis-Steele scan)
    int d = 0;
    if (t < HALF) { d = deg16[nbase + t]; scn[t] = d; }
    __syncthreads();
    for (int off = 1; off < HALF; off <<= 1) {
        int v = (t < HALF && t >= off) ? scn[t - off] : 0;
        __syncthreads();
        if (t < HALF) scn[t] += v;
        __syncthreads();
    }
    if (t < HALF) { int e = scn[t] - d; ofs[t] = e; cur[t] = e; }
    if (t == HALF - 1) ofs[HALF] = scn[HALF - 1];
    __syncthreads();

    // scatter own half's edges into LDS-sorted (node-grouped)
    int cnt = gcur[b];
    const int* bb = binned + b * STRIDE;
    for (int i = t; i < cnt; i += 512) {
        int v = bb[i];
        int dl = v >> SRCBITS;                 // 0..255 within bucket
        if ((dl >> 7) == halfSel) {
            int pos = atomicAdd(&cur[dl & (HALF - 1)], 1);
            sorted[pos] = v & SMASK;
        }
    }
    __syncthreads();

    // 4 lanes per node: register gather + reduce
    int ln = t >> 2;
    int lane = t & 3;
    int start = ofs[ln];
    int end = ofs[ln + 1];

    float acc[PERIODS];
    #pragma unroll
    for (int k = 0; k < PERIODS; ++k) acc[k] = 0.f;

    int i = start + lane;
    for (; i + 4 < end; i += 8) {              // x2: 2 gathers in flight
        int s0 = sorted[i];
        int s1 = sorted[i + 4];
        uint4 r0 = xs8[s0];
        uint4 r1 = xs8[s1];
        accdec(acc, r0);
        accdec(acc, r1);
    }
    if (i < end) {
        uint4 r0 = xs8[sorted[i]];
        accdec(acc, r0);
    }

    #pragma unroll
    for (int k = 0; k < PERIODS; ++k) {
        acc[k] += __shfl_xor(acc[k], 1);
        acc[k] += __shfl_xor(acc[k], 2);
    }

    int gn = nbase + ln;
    if (lane != 0 || gn >= N) return;

    {   // self term (di-scaled fp8 row)
        float f[PERIODS];
        uint4 r = xs8[gn];
        dec4(r.x, f + 0); dec4(r.y, f + 4); dec4(r.z, f + 8);
        #pragma unroll
        for (int k = 0; k < PERIODS; ++k) acc[k] += f[k];
    }

    float di = rsqrtf((float)(end - start) + 1.0f);
    float hacc[4] = {0.f, 0.f, 0.f, 0.f};
    #pragma unroll
    for (int p = 0; p < PERIODS; ++p) {
        float ap = di * acc[p];
        float pr = C->probs[p];
        #pragma unroll
        for (int c = 0; c < 4; ++c) {
            float zz = 1.f / (1.f + __expf(-(ap * C->az[c] + C->cz[c])));
            float hh = tanhf(ap * C->ah[c] + C->ch[c]);
            hacc[c] += pr * (1.f - zz) * hh;
        }
    }
    float o[PERIODS];
    #pragma unroll
    for (int f = 0; f < PERIODS; ++f) {
        float v = out_b[f];
        #pragma unroll
        for (int c = 0; c < 4; ++c) v += hacc[c] * out_w[c * PERIODS + f];
        o[f] = v;
    }
    float4* ov = (float4*)(out + (size_t)gn * PERIODS);
    ov[0] = make_float4(o[0], o[1], o[2],  o[3]);
    ov[1] = make_float4(o[4], o[5], o[6],  o[7]);
    ov[2] = make_float4(o[8], o[9], o[10], o[11]);
}

extern "C" void kernel_launch(void* const* d_in, const int* in_sizes, int n_in,
                              void* d_out, int out_size, void* d_ws, size_t ws_size,
                              hipStream_t stream) {
    const float* x        = (const float*)d_in[0];
    const int*   ei       = (const int*)d_in[1];
    const float* conv_z_w = (const float*)d_in[2];
    const float* conv_z_b = (const float*)d_in[3];
    const float* lin_z_w  = (const float*)d_in[4];
    const float* lin_z_b  = (const float*)d_in[5];
    const float* conv_h_w = (const float*)d_in[10];
    const float* conv_h_b = (const float*)d_in[11];
    const float* lin_h_w  = (const float*)d_in[12];
    const float* lin_h_b  = (const float*)d_in[13];
    const float* att      = (const float*)d_in[14];
    const float* out_w    = (const float*)d_in[15];
    const float* out_b    = (const float*)d_in[16];
    float* out = (float*)d_out;

    const int N    = in_sizes[0] / PERIODS;
    const int E    = in_sizes[1] / 2;
    const int NB   = (N + BSZ - 1) / BSZ;        // 391 buckets
    const int NPAD = NB * BSZ;                   // 100096
    const int gA   = (E + CH - 1) / CH;          // binning blocks

    // workspace layout (256B-aligned regions); total ~16.5 MB
    char* ws = (char*)d_ws;
    size_t off = 0;
    Consts*         consts = (Consts*)(ws + off);          off += (sizeof(Consts) + 255) & ~255ull;
    int*            gcur   = (int*)(ws + off);             off += ((size_t)NB * 4 + 255) & ~255ull;
    unsigned short* deg16  = (unsigned short*)(ws + off);  off += ((size_t)NPAD * 2 + 255) & ~255ull;
    uint4*          xs8    = (uint4*)(ws + off);           off += ((size_t)NPAD * 16 + 255) & ~255ull;
    int*            binned = (int*)(ws + off);             off += ((size_t)NB * STRIDE * 4 + 255) & ~255ull;
    (void)ws_size; (void)n_in; (void)out_size;

    k_setup<<<1, 512, 0, stream>>>(conv_z_w, conv_z_b, lin_z_w, lin_z_b,
                                   conv_h_w, conv_h_b, lin_h_w, lin_h_b, att,
                                   consts, gcur, NB, deg16, N, NPAD);
    k_binA<<<gA, 512, 0, stream>>>(ei, gcur, binned, E);
    k_prep<<<NB, 512, 0, stream>>>(binned, gcur, x, deg16, xs8, N);
    k_agg<<<NB * 2, 512, 0, stream>>>(binned, gcur, deg16, xs8, consts,
                                      out_w, out_b, out, N);
}